// Round 8
// baseline (272.160 us; speedup 1.0000x reference)
//
#include <hip/hip_runtime.h>

#define N_NODES 10000
#define N_EDGES 30000
#define DIN     64
#define EDIM    16
#define H1      128
#define H2      64
#define C_OUT   10

typedef __bf16 bfrag __attribute__((ext_vector_type(8)));
typedef float  f32x4 __attribute__((ext_vector_type(4)));
typedef ushort ushort8 __attribute__((ext_vector_type(8)));

__device__ __forceinline__ ushort f2bf(float f) {
    union { float f; unsigned u; } x; x.f = f;
    unsigned r = x.u + 0x7fffu + ((x.u >> 16) & 1u);   // RNE; inputs finite
    return (ushort)(r >> 16);
}
__device__ __forceinline__ float bf2f(ushort s) {
    union { unsigned u; float f; } x; x.u = ((unsigned)s) << 16;
    return x.f;
}

// ---------------------------------------------------------------------------
// kA: multi-role prep.
//   [0, 313):      h = relu(x@W1+b1) -> bf16, 32 nodes/block
//   [313, 889):    B1t permuted transpose (We1+root1+be1)
//   [889, 937):    B2t permuted transpose (We2+be2+root2)
//   [937, 977):    zero agg1 (grid-stride float4)
//   977:           edge bucketing: CSR of edges by src>>7 (79 buckets)
// NOTE (structural fact, R4/R5): persistent-kernel fusion with global
// barriers is pathological on MI355X (8 non-coherent XCD L2s -> wbL2+inv
// per barrier, ~200us each). Kernel boundaries ARE the cheapest barrier.
#define KA_B1   313
#define KA_B2   (KA_B1 + 576)
#define KA_B3   (KA_B2 + 48)
#define KA_B4   (KA_B3 + 40)
#define KA_TOT  (KA_B4 + 1)
__global__ __launch_bounds__(256) void kA_prep(
        const float* __restrict__ x, const float* __restrict__ W1,
        const float* __restrict__ b1,
        const float* __restrict__ We1, const float* __restrict__ root1,
        const float* __restrict__ be1,
        const float* __restrict__ We2, const float* __restrict__ be2,
        const float* __restrict__ root2, const int* __restrict__ src_idx,
        ushort* __restrict__ h_bf, ushort* __restrict__ B1t,
        ushort* __restrict__ B2t, float* __restrict__ agg1,
        int* __restrict__ row_ptr, int* __restrict__ ebuf) {
    int t = threadIdx.x;
    int bx = blockIdx.x;
    if (bx < KA_B1) {
        __shared__ float w_lds[DIN * H1];
        __shared__ float b_lds[H1];
        __shared__ float x_lds[8][DIN];
        for (int idx = t; idx < DIN * H1 / 4; idx += 256)
            ((float4*)w_lds)[idx] = ((const float4*)W1)[idx];
        if (t < H1) b_lds[t] = b1[t];
        #pragma unroll
        for (int sub = 0; sub < 4; ++sub) {
            int n0 = bx * 32 + sub * 8;
            if (t < 128) {
                int row = t >> 4, c4 = t & 15;
                int n = n0 + row;
                float4 v = make_float4(0.f, 0.f, 0.f, 0.f);
                if (n < N_NODES) v = ((const float4*)(x + (size_t)n * DIN))[c4];
                ((float4*)(x_lds[row]))[c4] = v;
            }
            __syncthreads();
            int nl = t >> 5;
            int o  = (t & 31) * 4;
            int n  = n0 + nl;
            float4 acc = *(const float4*)&b_lds[o];
            #pragma unroll 8
            for (int i = 0; i < DIN; ++i) {
                float xv = x_lds[nl][i];
                float4 w = *(const float4*)&w_lds[i * H1 + o];
                acc.x = fmaf(xv, w.x, acc.x);
                acc.y = fmaf(xv, w.y, acc.y);
                acc.z = fmaf(xv, w.z, acc.z);
                acc.w = fmaf(xv, w.w, acc.w);
            }
            if (n < N_NODES) {
                ushort4 s;
                s.x = f2bf(fmaxf(acc.x, 0.f));
                s.y = f2bf(fmaxf(acc.y, 0.f));
                s.z = f2bf(fmaxf(acc.z, 0.f));
                s.w = f2bf(fmaxf(acc.w, 0.f));
                *(ushort4*)&h_bf[(size_t)n * H1 + o] = s;
            }
            __syncthreads();
        }
    } else if (bx < KA_B2) {
        int idx = (bx - KA_B1) * 256 + t;
        int c = idx >> 7, i = idx & 127;
        float v;
        if (c < 1024) {
            int o = c >> 4, k = c & 15;              // permuted: c' = o*16 + k
            v = We1[(size_t)k * (H1 * H2) + i * 64 + o];
        } else if (c < 1088) v = root1[i * 64 + (c - 1024)];
        else                 v = be1[i * 64 + (c - 1088)];
        B1t[idx] = f2bf(v);
    } else if (bx < KA_B3) {
        int idx = (bx - KA_B2) * 256 + t;
        int c = idx >> 6, j = idx & 63;
        float v = 0.f;
        if (c < 160) {
            int cc = c >> 4, k = c & 15;             // permuted: c' = cc*16 + k
            v = We2[(size_t)k * 640 + j * 10 + cc];
        }
        else if (c < 170) v = be2[j * 10 + (c - 160)];
        else if (c < 180) v = root2[j * 10 + (c - 170)];
        B2t[idx] = f2bf(v);
    } else if (bx < KA_B4) {
        // zero agg1: 640,000 floats = 160,000 float4, 40 blocks grid-stride
        float4 z = make_float4(0.f, 0.f, 0.f, 0.f);
        for (int i = (bx - KA_B3) * 256 + t; i < 160000; i += 40 * 256)
            ((float4*)agg1)[i] = z;
    } else {
        // edge bucketing: CSR by src>>7 (79 buckets of 128 nodes)
        __shared__ int cnt[80];
        __shared__ int ofs[80];
        for (int i = t; i < 80; i += 256) cnt[i] = 0;
        __syncthreads();
        for (int e = t; e < N_EDGES; e += 256)
            atomicAdd(&cnt[src_idx[e] >> 7], 1);
        __syncthreads();
        if (t == 0) {
            int s = 0;
            for (int b = 0; b < 79; ++b) {
                ofs[b] = s; row_ptr[b] = s; s += cnt[b];
            }
            row_ptr[79] = s;   // == N_EDGES
        }
        __syncthreads();
        for (int e = t; e < N_EDGES; e += 256) {
            int p = atomicAdd(&ofs[src_idx[e] >> 7], 1);
            ebuf[p] = e;
        }
    }
}

// ---------------------------------------------------------------------------
// K34: merged k3+k4. Grid (79, 6). Block (mx, yy):
//  Phase A: MFMA GEMM for nodes [mx*128, +128), y-slice -> G1 slice in LDS
//    (o in [12yy, 12yy+12), or [60,64) for yy==5). yy==5 also atomicAdds the
//    root1+bias1 init into agg1 (agg1 pre-zeroed by kA; all-atomic, no race).
//    Mini 8-MFMA pass computes hb_slice = h @ be1[:, o-slice] into LDS.
//  Phase B: this block's src-bucket edges (kA CSR), thread-per-edge:
//    msg[o] = hb + sum_k ea[k]*G1_lds, atomicAdd to agg1.
// Eliminates G1t (20.5MB write + 61MB gather), hb1, one kernel boundary.
// LDS rows padded: G row 200 ushorts (400B, 16B-aligned, bank-rotates rows);
// hb row 17 floats.
__global__ __launch_bounds__(256) void k34_mfma_edge(
        const ushort* __restrict__ h_bf, const ushort* __restrict__ Bt,
        const float* __restrict__ bias1, const float* __restrict__ ea,
        const int* __restrict__ src_idx, const int* __restrict__ dst_idx,
        const int* __restrict__ row_ptr, const int* __restrict__ ebuf,
        float* __restrict__ agg1) {
    __shared__ ushort lds_G[128][200];   // [n_local][ol*16+k], 8-pad
    __shared__ float  lds_hb[128][17];   // [n_local][o - o0h], 1-pad
    int t = threadIdx.x;
    int wave = t >> 6, lane = t & 63;
    int quad = lane >> 4, lrow = lane & 15;
    int yy = blockIdx.y;
    int mx = blockIdx.x;
    int nblk = mx * 128;
    int nbase = nblk + wave * 32;
    int ar0 = nbase + lrow;       if (ar0 > N_NODES - 1) ar0 = N_NODES - 1;
    int ar1 = nbase + 16 + lrow;  if (ar1 > N_NODES - 1) ar1 = N_NODES - 1;
    // hoist A fragments (8 bfrags = 32 VGPRs)
    bfrag A0[4], A1[4];
    #pragma unroll
    for (int kc4 = 0; kc4 < 4; ++kc4) {
        A0[kc4] = *reinterpret_cast<const bfrag*>(
            h_bf + (size_t)ar0 * 128 + kc4 * 32 + quad * 8);
        A1[kc4] = *reinterpret_cast<const bfrag*>(
            h_bf + (size_t)ar1 * 128 + kc4 * 32 + quad * 8);
    }
    // ---- phase A: y-slices
    int ylim = (yy == 5) ? 2 : 3;        // yy==5: y=15 (G1), y=16 (agg init)
    for (int hy = 0; hy < ylim; ++hy) {
        int y = yy * 3 + hy;
        const ushort* bbase = Bt + (size_t)y * 64 * 128;
        f32x4 acc0[4] = {}, acc1[4] = {};
        #pragma unroll
        for (int kc4 = 0; kc4 < 4; ++kc4) {
            #pragma unroll
            for (int ct = 0; ct < 4; ++ct) {
                bfrag b = *reinterpret_cast<const bfrag*>(
                    bbase + (size_t)(ct * 16 + lrow) * 128 + kc4 * 32 + quad * 8);
                acc0[ct] = __builtin_amdgcn_mfma_f32_16x16x32_bf16(A0[kc4], b, acc0[ct], 0, 0, 0);
                acc1[ct] = __builtin_amdgcn_mfma_f32_16x16x32_bf16(A1[kc4], b, acc1[ct], 0, 0, 0);
            }
        }
        #pragma unroll
        for (int half = 0; half < 2; ++half) {
            int lbase = wave * 32 + half * 16 + quad * 4;
            #pragma unroll
            for (int ct = 0; ct < 4; ++ct) {
                int col = ct * 16 + lrow;
                f32x4 a = half ? acc1[ct] : acc0[ct];
                #pragma unroll
                for (int r = 0; r < 4; ++r) {
                    float v = a[r];
                    if (y < 16) {
                        lds_G[lbase + r][hy * 64 + col] = f2bf(v);
                    } else {  // y == 16: root1+bias1 fold, atomic onto zeroed agg1
                        int n = nblk + lbase + r;
                        if (n < N_NODES)
                            atomicAdd(&agg1[(size_t)n * 64 + col], v + bias1[col]);
                    }
                }
            }
        }
    }
    // ---- mini-pass: hb_slice = h @ be1[:, o0h..o0h+16) (B1t rows 1088+o)
    {
        int o0h = (yy == 5) ? 48 : 12 * yy;
        const ushort* bb = Bt + (size_t)(1088 + o0h) * 128;
        f32x4 h0 = {}, h1 = {};
        #pragma unroll
        for (int kc4 = 0; kc4 < 4; ++kc4) {
            bfrag b = *reinterpret_cast<const bfrag*>(
                bb + (size_t)lrow * 128 + kc4 * 32 + quad * 8);
            h0 = __builtin_amdgcn_mfma_f32_16x16x32_bf16(A0[kc4], b, h0, 0, 0, 0);
            h1 = __builtin_amdgcn_mfma_f32_16x16x32_bf16(A1[kc4], b, h1, 0, 0, 0);
        }
        #pragma unroll
        for (int half = 0; half < 2; ++half) {
            int lbase = wave * 32 + half * 16 + quad * 4;
            f32x4 a = half ? h1 : h0;
            #pragma unroll
            for (int r = 0; r < 4; ++r)
                lds_hb[lbase + r][lrow] = a[r];
        }
    }
    __syncthreads();
    // ---- phase B: this block's edge bucket, thread-per-edge
    int start = row_ptr[mx];
    int cnt   = row_ptr[mx + 1] - start;
    int W     = (yy == 5) ? 4 : 12;
    int o0    = (yy == 5) ? 60 : 12 * yy;
    int hboff = (yy == 5) ? 12 : 0;
    for (int i = t; i < cnt; i += 256) {
        int e = ebuf[start + i];
        int s = src_idx[e], d = dst_idx[e];
        int sl = s - nblk;
        const f32x4* ap = reinterpret_cast<const f32x4*>(ea + (size_t)e * 16);
        f32x4 a0 = ap[0], a1 = ap[1], a2 = ap[2], a3 = ap[3];
        for (int ol = 0; ol < W; ++ol) {
            ushort8 g0 = *reinterpret_cast<const ushort8*>(&lds_G[sl][ol * 16]);
            ushort8 g1 = *reinterpret_cast<const ushort8*>(&lds_G[sl][ol * 16 + 8]);
            float m = lds_hb[sl][ol + hboff];
            #pragma unroll
            for (int k = 0; k < 4; ++k) {
                m = fmaf(a0[k], bf2f(g0[k]), m);
                m = fmaf(a1[k], bf2f(g0[k + 4]), m);
                m = fmaf(a2[k], bf2f(g1[k]), m);
                m = fmaf(a3[k], bf2f(g1[k + 4]), m);
            }
            atomicAdd(&agg1[(size_t)d * 64 + o0 + ol], m);
        }
    }
}

// ---------------------------------------------------------------------------
// K56: layer-2 node GEMM via MFMA, grid (157). G2t stored BF16.
// cg in [170,180) writes v+bias2 DIRECTLY into agg2 (k7 atomics on top).
__global__ __launch_bounds__(256) void k56_mfma(
        const float* __restrict__ agg1, const ushort* __restrict__ B2t,
        const float* __restrict__ bias2,
        ushort* __restrict__ G2t, float* __restrict__ hb2,
        float* __restrict__ agg2) {
    int t = threadIdx.x;
    int wave = t >> 6, lane = t & 63;
    int quad = lane >> 4, lrow = lane & 15;
    int n0 = blockIdx.x * 64 + wave * 16;
    int arow = n0 + lrow; if (arow > N_NODES - 1) arow = N_NODES - 1;
    bfrag A[2];
    #pragma unroll
    for (int kk = 0; kk < 2; ++kk) {
        size_t off = (size_t)arow * 64 + kk * 32 + quad * 8;
        f32x4 p0 = *(const f32x4*)(agg1 + off);
        f32x4 p1 = *(const f32x4*)(agg1 + off + 4);
        bfrag a;
        #pragma unroll
        for (int j = 0; j < 4; ++j) {
            a[j]     = (__bf16)fmaxf(p0[j], 0.f);
            a[j + 4] = (__bf16)fmaxf(p1[j], 0.f);
        }
        A[kk] = a;
    }
    #pragma unroll
    for (int y = 0; y < 3; ++y) {
        f32x4 acc[4] = {};
        #pragma unroll
        for (int kk = 0; kk < 2; ++kk) {
            #pragma unroll
            for (int ct = 0; ct < 4; ++ct) {
                bfrag b = *reinterpret_cast<const bfrag*>(
                    B2t + (size_t)(y * 64 + ct * 16 + lrow) * 64 + kk * 32 + quad * 8);
                acc[ct] = __builtin_amdgcn_mfma_f32_16x16x32_bf16(A[kk], b, acc[ct], 0, 0, 0);
            }
        }
        #pragma unroll
        for (int ct = 0; ct < 4; ++ct) {
            int cg = y * 64 + ct * 16 + lrow;
            #pragma unroll
            for (int r = 0; r < 4; ++r) {
                int n = n0 + quad * 4 + r;
                if (n >= N_NODES) continue;
                float v = acc[ct][r];
                if (cg < 160)      G2t[(size_t)n * 160 + cg] = f2bf(v);   // bf16
                else if (cg < 170) hb2[(size_t)n * 10 + (cg - 160)] = v;
                else if (cg < 180) agg2[(size_t)n * 10 + (cg - 170)] = v + bias2[cg - 170];
            }
        }
    }
}

// ---------------------------------------------------------------------------
// K7: edge pass 2. thread per (edge, class): 10 threads/edge. G2t bf16.
__global__ __launch_bounds__(256) void k7_edge2(
        const float* __restrict__ ea, const int* __restrict__ src_idx,
        const int* __restrict__ dst_idx, const ushort* __restrict__ G2t,
        const float* __restrict__ hb2, float* __restrict__ agg2) {
    int tid = blockIdx.x * 256 + threadIdx.x;
    if (tid >= N_EDGES * 10) return;
    int e = tid / 10, c = tid - e * 10;
    int s = src_idx[e], d = dst_idx[e];
    float m = hb2[(size_t)s * 10 + c];
    const ushort* g = G2t + (size_t)s * 160 + c * 16;
    ushort8 g0 = *reinterpret_cast<const ushort8*>(g);
    ushort8 g1 = *reinterpret_cast<const ushort8*>(g + 8);
    const float* a = ea + (size_t)e * 16;
    f32x4 a0 = *(const f32x4*)a,       a1 = *(const f32x4*)(a + 4);
    f32x4 a2 = *(const f32x4*)(a + 8), a3 = *(const f32x4*)(a + 12);
    #pragma unroll
    for (int k = 0; k < 4; ++k) {
        m = fmaf(a0[k], bf2f(g0[k]), m);
        m = fmaf(a1[k], bf2f(g0[k + 4]), m);
        m = fmaf(a2[k], bf2f(g1[k]), m);
        m = fmaf(a3[k], bf2f(g1[k + 4]), m);
    }
    atomicAdd(&agg2[(size_t)d * 10 + c], m);
}

// ---------------------------------------------------------------------------
// K8: out = log_softmax(agg2)  (agg2 already holds z = agg + root + bias)
__global__ void k8_logsoftmax(const float* __restrict__ agg2,
                              float* __restrict__ out) {
    int n = blockIdx.x * blockDim.x + threadIdx.x;
    if (n >= N_NODES) return;
    float z[10]; float m = -1e30f;
    #pragma unroll
    for (int c = 0; c < 10; ++c) {
        z[c] = agg2[(size_t)n * 10 + c];
        m = fmaxf(m, z[c]);
    }
    float s = 0.f;
    #pragma unroll
    for (int c = 0; c < 10; ++c) s += expf(z[c] - m);
    float ls = logf(s);
    #pragma unroll
    for (int c = 0; c < 10; ++c) out[(size_t)n * 10 + c] = z[c] - m - ls;
}

// ---------------------------------------------------------------------------
extern "C" void kernel_launch(void* const* d_in, const int* in_sizes, int n_in,
                              void* d_out, int out_size, void* d_ws, size_t ws_size,
                              hipStream_t stream) {
    const float* x     = (const float*)d_in[0];
    const float* ea    = (const float*)d_in[1];
    const int*   eidx  = (const int*)d_in[2];
    const float* W1    = (const float*)d_in[3];
    const float* b1    = (const float*)d_in[4];
    const float* We1   = (const float*)d_in[5];
    const float* be1   = (const float*)d_in[6];
    const float* root1 = (const float*)d_in[7];
    const float* bias1 = (const float*)d_in[8];
    const float* We2   = (const float*)d_in[9];
    const float* be2   = (const float*)d_in[10];
    const float* root2 = (const float*)d_in[11];
    const float* bias2 = (const float*)d_in[12];
    float* out = (float*)d_out;
    const int* src_idx = eidx;
    const int* dst_idx = eidx + N_EDGES;

    // workspace layout (float units, all 16B-aligned)
    float* ws = (float*)d_ws;
    ushort* h_bf = (ushort*)ws;                        // 1,280,000 us = 640,000 f
    ushort* B1t  = (ushort*)(ws + 640000);             // 147,456 us = 73,728 f
    ushort* B2t  = (ushort*)(ws + 713728);             // 12,288 us = 6,144 f
    int* ebuf    = (int*)(ws + 719872);                // 30,000 i (30,016 f resv)
    int* row_ptr = (int*)(ws + 749888);                // 80 i (96 f resv)
    float* agg1 = ws + 749984;                         // 640,000
    float* agg2 = agg1 + 640000;                       // 100,000
    ushort* G2t = (ushort*)(agg2 + 100000);            // 1,600,000 us = 800,000 f
    float* hb2  = agg2 + 100000 + 800000;              // 100,000  (R7 BUG: was +400000 -> hb2 overlapped G2t upper half)

    kA_prep<<<KA_TOT, 256, 0, stream>>>(x, W1, b1, We1, root1, be1,
                                        We2, be2, root2, src_idx,
                                        h_bf, B1t, B2t, agg1, row_ptr, ebuf);
    k34_mfma_edge<<<dim3(79, 6), 256, 0, stream>>>(h_bf, B1t, bias1, ea,
                                                   src_idx, dst_idx,
                                                   row_ptr, ebuf, agg1);
    k56_mfma<<<157, 256, 0, stream>>>(agg1, B2t, bias2, G2t, hb2, agg2);
    k7_edge2<<<1172, 256, 0, stream>>>(ea, src_idx, dst_idx, G2t, hb2, agg2);
    k8_logsoftmax<<<40, 256, 0, stream>>>(agg2, out);
}